// Round 9
// baseline (115.191 us; speedup 1.0000x reference)
//
#include <hip/hip_runtime.h>

#define kNW 4096
#define kTC 24
#define kCL 8       // outputs per chunk (word-LSTM)
#define kBURN 32    // burn-in steps before each chunk

typedef float v2f __attribute__((ext_vector_type(2)));

// ws layout (float offsets)
#define XE_OFF   0u         // [2][128][128]  char input-proj tables (bias folded)
#define WH_OFF   32768u     // [2][4096][32]  char-LSTM final hidden per word
#define ENC_OFF  2392064u   // [2][4096][64]  sigmoid(bilstm) encodings

__device__ __forceinline__ float fsig(float x){
  return __builtin_amdgcn_rcpf(1.f + __builtin_amdgcn_exp2f(-1.44269504f * x));
}
__device__ __forceinline__ float ftanh_(float x){
  return fmaf(2.f, __builtin_amdgcn_rcpf(1.f + __builtin_amdgcn_exp2f(-2.88539008f * x)), -1.f);
}

// ---------------- K0: char input-proj tables, coalesced shfl-reduce ----------------
__global__ __launch_bounds__(256) void k_tables(
    const float* __restrict__ embed_e, const float* __restrict__ embed_f,
    const float* __restrict__ Wih_e, const float* __restrict__ b_e,
    const float* __restrict__ Wih_f, const float* __restrict__ b_f,
    float* __restrict__ ws)
{
  int lane = threadIdx.x & 63;
  int wv   = threadIdx.x >> 6;
  int gw   = blockIdx.x * 4 + wv;            // 0..4095
  int side = gw >> 11;
  int c    = (gw & 2047) >> 4;
  int g0   = (gw & 15) * 8;
  const float* er = (side ? embed_f : embed_e) + c * 128;
  const float* Wih = side ? Wih_f : Wih_e;
  const float* bb  = side ? b_f   : b_e;
  float* X = ws + XE_OFF + side * 16384 + c * 128;

  float ea = er[lane], eb = er[lane + 64];
  #pragma unroll
  for (int i = 0; i < 8; ++i){
    const float* wr = Wih + (g0 + i) * 128;
    float p = ea * wr[lane] + eb * wr[lane + 64];
    #pragma unroll
    for (int m = 1; m < 64; m <<= 1) p += __shfl_xor(p, m, 64);
    if (lane == 0) X[g0 + i] = bb[g0 + i] + p;
  }
}

// ---------------- K1: char LSTM v2 — 2 words/wave, 4 gates/lane, NO cross-lane ----------------
// lane = (half, col): computes i,f,g,o for column `col` of word `2*bid+half` as two
// v2f chains; the LSTM recombination is lane-local (deletes both ds_bpermutes).
__global__ __launch_bounds__(64) __attribute__((amdgpu_waves_per_eu(2, 4)))
void k_char(
    const int* __restrict__ e_chars, const int* __restrict__ e_lens,
    const int* __restrict__ f_chars, const int* __restrict__ f_lens,
    const float* __restrict__ Whh_e, const float* __restrict__ Whh_f,
    float* __restrict__ ws)
{
  int side = blockIdx.y;
  const int* chars = side ? f_chars : e_chars;
  const int* lens  = side ? f_lens  : e_lens;
  const float* Whh = side ? Whh_f : Whh_e;
  const float* X   = ws + XE_OFF + side * 16384;
  float* wh        = ws + WH_OFF + side * 131072;

  int lane = threadIdx.x;
  int half = lane >> 5;
  int col  = lane & 31;
  int word = blockIdx.x * 2 + half;

  __shared__ __align__(16) float hl[2][32];

  // gate rows (i=col, f=col+32) and (g=col+64, o=col+96) as v2f pairs
  v2f wif[32], wgo[32];
  #pragma unroll
  for (int q = 0; q < 8; ++q){
    float4 ai = *(const float4*)(Whh + col * 32 + q * 4);
    float4 af = *(const float4*)(Whh + (col + 32) * 32 + q * 4);
    float4 ag = *(const float4*)(Whh + (col + 64) * 32 + q * 4);
    float4 ao = *(const float4*)(Whh + (col + 96) * 32 + q * 4);
    wif[q*4+0] = (v2f){ai.x, af.x}; wif[q*4+1] = (v2f){ai.y, af.y};
    wif[q*4+2] = (v2f){ai.z, af.z}; wif[q*4+3] = (v2f){ai.w, af.w};
    wgo[q*4+0] = (v2f){ag.x, ao.x}; wgo[q*4+1] = (v2f){ag.y, ao.y};
    wgo[q*4+2] = (v2f){ag.z, ao.z}; wgo[q*4+3] = (v2f){ag.w, ao.w};
  }
  hl[half][col] = 0.f;                    // 64 distinct slots
  float cst = 0.f, h2 = 0.f;
  int len = lens[word];                   // uniform within half
  int l0 = __shfl(len, 0, 64), l1 = __shfl(len, 32, 64);
  int lenmax = l0 > l1 ? l0 : l1;

  int ch = chars[word * kTC];
  float xi = X[ch*128 + col],      xf = X[ch*128 + 32 + col];
  float xg = X[ch*128 + 64 + col], xo = X[ch*128 + 96 + col];

  for (int t = 0; t < lenmax; ++t){
    v2f qif0 = (v2f){xi, xf}, qgo0 = (v2f){xg, xo};
    if (t + 1 < lenmax){                  // prefetch next char (clamped)
      int tn = (t + 1 < len) ? (t + 1) : (len - 1);
      int cn = chars[word * kTC + tn];
      xi = X[cn*128 + col];      xf = X[cn*128 + 32 + col];
      xg = X[cn*128 + 64 + col]; xo = X[cn*128 + 96 + col];
    }
    float hbf[32];
    #pragma unroll
    for (int q = 0; q < 8; ++q){
      float4 hv = *(const float4*)(&hl[half][q*4]);
      hbf[q*4+0]=hv.x; hbf[q*4+1]=hv.y; hbf[q*4+2]=hv.z; hbf[q*4+3]=hv.w;
    }
    v2f qif1 = (v2f){0.f,0.f}, qgo1 = (v2f){0.f,0.f};
    #pragma unroll
    for (int k = 0; k < 16; ++k){
      v2f h0 = (v2f){hbf[k],    hbf[k]};
      v2f h1 = (v2f){hbf[k+16], hbf[k+16]};
      qif0 = __builtin_elementwise_fma(wif[k],    h0, qif0);
      qif1 = __builtin_elementwise_fma(wif[k+16], h1, qif1);
      qgo0 = __builtin_elementwise_fma(wgo[k],    h0, qgo0);
      qgo1 = __builtin_elementwise_fma(wgo[k+16], h1, qgo1);
    }
    v2f qif = qif0 + qif1, qgo = qgo0 + qgo1;
    float si = fsig(qif.x), sf = fsig(qif.y);
    float tg = ftanh_(qgo.x), so = fsig(qgo.y);
    if (t < len){                         // half-granular predication
      cst = fmaf(sf, cst, si * tg);
      h2  = so * ftanh_(cst);
      hl[half][col] = h2;
    }
  }
  wh[(size_t)word * 32 + col] = h2;
}

// ---------------- K2: word BiLSTM v2 — proj fused, one exchange/step ----------------
// Chunk stages its <=40 wh rows to LDS once; per step computes the input proj
// in-register (independent pk-FMAs hide under recurrence latency). Lo lanes send
// m = sig(i)*tanh(g); hi lanes (f,o) own cst/h and write enc.
__global__ __launch_bounds__(64) __attribute__((amdgpu_waves_per_eu(2, 4)))
void k_word_par(
    const float* __restrict__ Whh0, const float* __restrict__ Whh1,
    const float* __restrict__ Whh2, const float* __restrict__ Whh3,
    const float* __restrict__ Wih0, const float* __restrict__ b0,
    const float* __restrict__ Wih1, const float* __restrict__ b1,
    const float* __restrict__ Wih2, const float* __restrict__ b2,
    const float* __restrict__ Wih3, const float* __restrict__ b3,
    float* __restrict__ ws)
{
  int qk  = blockIdx.x;              // chunk id 0..511
  int dir = blockIdx.y;              // 0..3
  const float* Whh = dir==0?Whh0 : dir==1?Whh1 : dir==2?Whh2 : Whh3;
  const float* Wih = dir==0?Wih0 : dir==1?Wih1 : dir==2?Wih2 : Wih3;
  const float* bb  = dir==0?b0  : dir==1?b1  : dir==2?b2  : b3;
  int side = dir >> 1, bwd = dir & 1;
  const float* wh = ws + WH_OFF + side * 131072;
  float* enc = ws + ENC_OFF + side * 262144 + (bwd ? 32 : 0);
  int lane = threadIdx.x;

  __shared__ __align__(16) float hl[32];
  __shared__ __align__(16) float whs[kBURN + kCL][32];

  int tauOut = qk * kCL;
  int tau0   = tauOut - kBURN; if (tau0 < 0) tau0 = 0;
  int tauEnd = tauOut + kCL;
  int n = tauEnd - tau0;

  auto POS = [&](int tau){ return bwd ? (kNW - 1 - tau) : tau; };

  // stage wh rows for this chunk (row j = logical step tau0+j)
  for (int i = lane; i < n * 32; i += 64){
    int j = i >> 5, k = i & 31;
    whs[j][k] = wh[(size_t)POS(tau0 + j) * 32 + k];
  }

  // recurrent rows (lane, lane+64) and proj rows (lane, lane+64), adjacent-k v2f pairs
  v2f wA[16], wB[16], pA[16], pB[16];
  #pragma unroll
  for (int q = 0; q < 8; ++q){
    float4 a  = *(const float4*)(Whh + lane * 32 + q * 4);
    float4 b4 = *(const float4*)(Whh + (lane + 64) * 32 + q * 4);
    wA[q*2+0] = (v2f){a.x, a.y};   wA[q*2+1] = (v2f){a.z, a.w};
    wB[q*2+0] = (v2f){b4.x, b4.y}; wB[q*2+1] = (v2f){b4.z, b4.w};
    float4 c4 = *(const float4*)(Wih + lane * 32 + q * 4);
    float4 d4 = *(const float4*)(Wih + (lane + 64) * 32 + q * 4);
    pA[q*2+0] = (v2f){c4.x, c4.y}; pA[q*2+1] = (v2f){c4.z, c4.w};
    pB[q*2+0] = (v2f){d4.x, d4.y}; pB[q*2+1] = (v2f){d4.z, d4.w};
  }
  float bA = bb[lane], bB = bb[lane + 64];
  if (lane < 32) hl[lane] = 0.f;
  float cst = 0.f;
  float kB = (lane < 32) ? -2.88539008f : -1.44269504f;
  float cB = (lane < 32) ? 2.f : 1.f;
  float dB = (lane < 32) ? -1.f : 0.f;

  for (int j = 0; j < n; ++j){
    int tau = tau0 + j;
    // ---- input proj from whs[j] (independent of recurrence) ----
    v2f w2[16];
    #pragma unroll
    for (int q = 0; q < 8; ++q){
      float4 wv = *(const float4*)(&whs[j][q*4]);
      w2[q*2+0] = (v2f){wv.x, wv.y}; w2[q*2+1] = (v2f){wv.z, wv.w};
    }
    v2f sa0 = {0.f,0.f}, sa1 = {0.f,0.f}, sb0 = {0.f,0.f}, sb1 = {0.f,0.f};
    #pragma unroll
    for (int k = 0; k < 8; ++k){
      sa0 = __builtin_elementwise_fma(pA[k],   w2[k],   sa0);
      sa1 = __builtin_elementwise_fma(pA[k+8], w2[k+8], sa1);
      sb0 = __builtin_elementwise_fma(pB[k],   w2[k],   sb0);
      sb1 = __builtin_elementwise_fma(pB[k+8], w2[k+8], sb1);
    }
    // ---- recurrent matvec from hl ----
    v2f hb[16];
    #pragma unroll
    for (int q = 0; q < 8; ++q){
      float4 hv = *(const float4*)(&hl[q*4]);
      hb[q*2+0] = (v2f){hv.x, hv.y}; hb[q*2+1] = (v2f){hv.z, hv.w};
    }
    v2f qa0 = {0.f,0.f}, qa1 = {0.f,0.f}, qb0 = {0.f,0.f}, qb1 = {0.f,0.f};
    #pragma unroll
    for (int k = 0; k < 8; ++k){
      qa0 = __builtin_elementwise_fma(wA[k],   hb[k],   qa0);
      qa1 = __builtin_elementwise_fma(wA[k+8], hb[k+8], qa1);
      qb0 = __builtin_elementwise_fma(wB[k],   hb[k],   qb0);
      qb1 = __builtin_elementwise_fma(wB[k+8], hb[k+8], qb1);
    }
    v2f va = (qa0 + qa1) + (sa0 + sa1);
    v2f vb = (qb0 + qb1) + (sb0 + sb1);
    float accA = bA + va.x + va.y;
    float accB = bB + vb.x + vb.y;
    float sA = fsig(accA);   // lanes<32: sig(i);  lanes>=32: sig(f)
    float sB = fmaf(cB, __builtin_amdgcn_rcpf(1.f + __builtin_amdgcn_exp2f(kB * accB)), dB);
                             // lanes<32: tanh(g); lanes>=32: sig(o)
    float m   = sA * sB;                        // lo lanes: i*g~
    float mex = __shfl(m, lane & 31, 64);       // broadcast lo half upward
    cst = fmaf(sA, cst, mex);                   // hi lanes: f*c + m
    float h2 = sB * ftanh_(cst);                // hi lanes: o*tanh(c)
    if (lane >= 32){
      hl[lane - 32] = h2;
      if (tau >= tauOut) enc[(size_t)POS(tau) * 64 + (lane - 32)] = fsig(h2);
    }
  }
}

// ---------------- K3: out = f_enc @ e_enc.T  (K=64), 128x128 tiles, pk-f32 ----------------
__global__ __launch_bounds__(256) __attribute__((amdgpu_waves_per_eu(2, 4)))
void k_mm(const float* __restrict__ ws, float* __restrict__ out)
{
  const float* e_enc = ws + ENC_OFF;
  const float* f_enc = ws + ENC_OFF + 262144;
  __shared__ __align__(16) float fS[64][128];
  __shared__ __align__(16) float eS[64][128];
  int t = threadIdx.x;
  int row0 = blockIdx.y * 128;
  int col0 = blockIdx.x * 128;
  {
    int r = t & 127, kh = t >> 7;
    const float* fsrc = f_enc + (size_t)(row0 + r) * 64 + kh * 32;
    const float* esrc = e_enc + (size_t)(col0 + r) * 64 + kh * 32;
    #pragma unroll
    for (int q = 0; q < 8; ++q){
      float4 v = *(const float4*)(fsrc + q * 4);
      int k = kh * 32 + q * 4;
      fS[k+0][r] = v.x; fS[k+1][r] = v.y; fS[k+2][r] = v.z; fS[k+3][r] = v.w;
      float4 u = *(const float4*)(esrc + q * 4);
      eS[k+0][r] = u.x; eS[k+1][r] = u.y; eS[k+2][r] = u.z; eS[k+3][r] = u.w;
    }
  }
  __syncthreads();
  int tx = t & 15, ty = t >> 4;
  int r0 = ty * 8, c0 = tx * 8;
  v2f acc2[8][4];
  #pragma unroll
  for (int i = 0; i < 8; ++i)
    #pragma unroll
    for (int j = 0; j < 4; ++j) acc2[i][j] = (v2f){0.f, 0.f};

  #pragma unroll 4
  for (int k = 0; k < 64; ++k){
    float4 fa = *(const float4*)(&fS[k][r0]);
    float4 fb = *(const float4*)(&fS[k][r0 + 4]);
    float4 ea = *(const float4*)(&eS[k][c0]);
    float4 eb = *(const float4*)(&eS[k][c0 + 4]);
    float fr[8] = {fa.x, fa.y, fa.z, fa.w, fb.x, fb.y, fb.z, fb.w};
    v2f e2[4] = {(v2f){ea.x, ea.y}, (v2f){ea.z, ea.w},
                 (v2f){eb.x, eb.y}, (v2f){eb.z, eb.w}};
    #pragma unroll
    for (int i = 0; i < 8; ++i){
      v2f f2 = (v2f){fr[i], fr[i]};
      #pragma unroll
      for (int j = 0; j < 4; ++j)
        acc2[i][j] = __builtin_elementwise_fma(f2, e2[j], acc2[i][j]);
    }
  }
  #pragma unroll
  for (int i = 0; i < 8; ++i){
    float* dst = out + (size_t)(row0 + r0 + i) * 4096 + col0 + c0;
    *(float4*)(dst)     = make_float4(acc2[i][0].x, acc2[i][0].y, acc2[i][1].x, acc2[i][1].y);
    *(float4*)(dst + 4) = make_float4(acc2[i][2].x, acc2[i][2].y, acc2[i][3].x, acc2[i][3].y);
  }
}

extern "C" void kernel_launch(void* const* d_in, const int* in_sizes, int n_in,
                              void* d_out, int out_size, void* d_ws, size_t ws_size,
                              hipStream_t stream)
{
  const int* e_chars = (const int*)d_in[0];
  const int* e_lens  = (const int*)d_in[1];
  const int* f_chars = (const int*)d_in[2];
  const int* f_lens  = (const int*)d_in[3];
  // d_in[4] = diag (unused by reference)
  const float* embed_e = (const float*)d_in[5];
  const float* embed_f = (const float*)d_in[6];
  const float* eC_ih = (const float*)d_in[7];
  const float* eC_hh = (const float*)d_in[8];
  const float* eC_b  = (const float*)d_in[9];
  const float* fC_ih = (const float*)d_in[10];
  const float* fC_hh = (const float*)d_in[11];
  const float* fC_b  = (const float*)d_in[12];
  const float* efw_ih = (const float*)d_in[13];
  const float* efw_hh = (const float*)d_in[14];
  const float* efw_b  = (const float*)d_in[15];
  const float* ebw_ih = (const float*)d_in[16];
  const float* ebw_hh = (const float*)d_in[17];
  const float* ebw_b  = (const float*)d_in[18];
  const float* ffw_ih = (const float*)d_in[19];
  const float* ffw_hh = (const float*)d_in[20];
  const float* ffw_b  = (const float*)d_in[21];
  const float* fbw_ih = (const float*)d_in[22];
  const float* fbw_hh = (const float*)d_in[23];
  const float* fbw_b  = (const float*)d_in[24];
  float* ws  = (float*)d_ws;
  float* out = (float*)d_out;

  hipLaunchKernelGGL(k_tables, dim3(1024), dim3(256), 0, stream,
                     embed_e, embed_f, eC_ih, eC_b, fC_ih, fC_b, ws);
  hipLaunchKernelGGL(k_char, dim3(2048, 2), dim3(64), 0, stream,
                     e_chars, e_lens, f_chars, f_lens, eC_hh, fC_hh, ws);
  hipLaunchKernelGGL(k_word_par, dim3(kNW / kCL, 4), dim3(64), 0, stream,
                     efw_hh, ebw_hh, ffw_hh, fbw_hh,
                     efw_ih, efw_b, ebw_ih, ebw_b, ffw_ih, ffw_b, fbw_ih, fbw_b, ws);
  hipLaunchKernelGGL(k_mm, dim3(32, 32), dim3(256), 0, stream, ws, out);
}

// Round 10
// 107.288 us; speedup vs baseline: 1.0737x; 1.0737x over previous
//
#include <hip/hip_runtime.h>

#define kNW 4096
#define kTC 24
#define kCL 8       // outputs per chunk (word-LSTM)
#define kBURN 32    // burn-in steps before each chunk

typedef float v2f __attribute__((ext_vector_type(2)));

// ws layout (float offsets)
#define XE_OFF   0u         // [2][128][128]  char input-proj tables (bias folded)
#define WH_OFF   32768u     // [2][4096][32]  char-LSTM final hidden per word
#define ENC_OFF  2392064u   // [2][4096][64]  sigmoid(bilstm) encodings

__device__ __forceinline__ float fsig(float x){
  return __builtin_amdgcn_rcpf(1.f + __builtin_amdgcn_exp2f(-1.44269504f * x));
}
__device__ __forceinline__ float ftanh_(float x){
  return fmaf(2.f, __builtin_amdgcn_rcpf(1.f + __builtin_amdgcn_exp2f(-2.88539008f * x)), -1.f);
}

// ---------------- K0: char input-proj tables, coalesced shfl-reduce ----------------
__global__ __launch_bounds__(256) void k_tables(
    const float* __restrict__ embed_e, const float* __restrict__ embed_f,
    const float* __restrict__ Wih_e, const float* __restrict__ b_e,
    const float* __restrict__ Wih_f, const float* __restrict__ b_f,
    float* __restrict__ ws)
{
  int lane = threadIdx.x & 63;
  int wv   = threadIdx.x >> 6;
  int gw   = blockIdx.x * 4 + wv;            // 0..4095
  int side = gw >> 11;
  int c    = (gw & 2047) >> 4;
  int g0   = (gw & 15) * 8;
  const float* er = (side ? embed_f : embed_e) + c * 128;
  const float* Wih = side ? Wih_f : Wih_e;
  const float* bb  = side ? b_f   : b_e;
  float* X = ws + XE_OFF + side * 16384 + c * 128;

  float ea = er[lane], eb = er[lane + 64];
  #pragma unroll
  for (int i = 0; i < 8; ++i){
    const float* wr = Wih + (g0 + i) * 128;
    float p = ea * wr[lane] + eb * wr[lane + 64];
    #pragma unroll
    for (int m = 1; m < 64; m <<= 1) p += __shfl_xor(p, m, 64);
    if (lane == 0) X[g0 + i] = bb[g0 + i] + p;
  }
}

// ---------------- K1: char LSTM v3 — 1 word/wave, lane-pair gate split ----------------
// lane L<32 owns rows L (i) and L+64 (g); lane L+32 owns rows L+32 (f), L+96 (o).
// 64 weight VGPRs/lane; one __shfl exchange (lo sends m=sig(i)*tanh(g), hi owns c,h).
// waves_per_eu(1,2): VGPR budget 512 (cap 256 at 2 waves) -> no spill/remat incentive.
__global__ __launch_bounds__(64) __attribute__((amdgpu_waves_per_eu(1, 2)))
void k_char(
    const int* __restrict__ e_chars, const int* __restrict__ e_lens,
    const int* __restrict__ f_chars, const int* __restrict__ f_lens,
    const float* __restrict__ Whh_e, const float* __restrict__ Whh_f,
    float* __restrict__ ws)
{
  int side = blockIdx.y;
  const int* chars = side ? f_chars : e_chars;
  const int* lens  = side ? f_lens  : e_lens;
  const float* Whh = side ? Whh_f : Whh_e;
  const float* X   = ws + XE_OFF + side * 16384;
  float* wh        = ws + WH_OFF + side * 131072;

  int lane = threadIdx.x;
  int col  = lane & 31;
  int word = blockIdx.x;

  __shared__ __align__(16) float hl[32];

  v2f wA[16], wB[16];
  #pragma unroll
  for (int q = 0; q < 8; ++q){
    float4 a  = *(const float4*)(Whh + lane * 32 + q * 4);
    float4 b4 = *(const float4*)(Whh + (lane + 64) * 32 + q * 4);
    wA[q*2+0] = (v2f){a.x, a.y};   wA[q*2+1] = (v2f){a.z, a.w};
    wB[q*2+0] = (v2f){b4.x, b4.y}; wB[q*2+1] = (v2f){b4.z, b4.w};
  }
  if (lane < 32) hl[lane] = 0.f;
  float cst = 0.f, h2 = 0.f;
  int len = __builtin_amdgcn_readfirstlane(lens[word]);
  // accB nonlinearity: lanes<32 -> tanh(g), lanes>=32 -> sigmoid(o)
  float kB = (lane < 32) ? -2.88539008f : -1.44269504f;
  float cB = (lane < 32) ? 2.f : 1.f;
  float dB = (lane < 32) ? -1.f : 0.f;

  int ch0 = __builtin_amdgcn_readfirstlane(chars[word * kTC]);
  float xa = X[ch0 * 128 + lane];
  float xb = X[ch0 * 128 + 64 + lane];

  for (int t = 0; t < len; ++t){
    float accA0 = xa, accB0 = xb;
    if (t + 1 < len){
      int cn = __builtin_amdgcn_readfirstlane(chars[word * kTC + t + 1]);
      xa = X[cn * 128 + lane];
      xb = X[cn * 128 + 64 + lane];
    }
    v2f hb[16];
    #pragma unroll
    for (int q = 0; q < 8; ++q){
      float4 hv = *(const float4*)(&hl[q * 4]);
      hb[q*2+0] = (v2f){hv.x, hv.y}; hb[q*2+1] = (v2f){hv.z, hv.w};
    }
    v2f qa0 = {0.f,0.f}, qa1 = {0.f,0.f}, qb0 = {0.f,0.f}, qb1 = {0.f,0.f};
    #pragma unroll
    for (int k = 0; k < 8; ++k){
      qa0 = __builtin_elementwise_fma(wA[k],   hb[k],   qa0);
      qa1 = __builtin_elementwise_fma(wA[k+8], hb[k+8], qa1);
      qb0 = __builtin_elementwise_fma(wB[k],   hb[k],   qb0);
      qb1 = __builtin_elementwise_fma(wB[k+8], hb[k+8], qb1);
    }
    v2f va = qa0 + qa1, vb = qb0 + qb1;
    float accA = accA0 + va.x + va.y;     // lo: i-preact, hi: f-preact
    float accB = accB0 + vb.x + vb.y;     // lo: g-preact, hi: o-preact
    float sA = fsig(accA);                // lo: sig(i), hi: sig(f)
    float sB = fmaf(cB, __builtin_amdgcn_rcpf(1.f + __builtin_amdgcn_exp2f(kB * accB)), dB);
                                          // lo: tanh(g), hi: sig(o)
    float m   = sA * sB;                  // lo: i*g~
    float mex = __shfl(m, col, 64);       // hi gets lo partner's m
    cst = fmaf(sA, cst, mex);             // hi: f*c + m
    h2  = sB * ftanh_(cst);               // hi: o*tanh(c)
    if (lane >= 32) hl[col] = h2;
  }
  if (lane >= 32) wh[(size_t)word * 32 + col] = h2;
}

// ---------------- K2: word BiLSTM v2 — proj fused, one exchange/step ----------------
__global__ __launch_bounds__(64) __attribute__((amdgpu_waves_per_eu(1, 2)))
void k_word_par(
    const float* __restrict__ Whh0, const float* __restrict__ Whh1,
    const float* __restrict__ Whh2, const float* __restrict__ Whh3,
    const float* __restrict__ Wih0, const float* __restrict__ b0,
    const float* __restrict__ Wih1, const float* __restrict__ b1,
    const float* __restrict__ Wih2, const float* __restrict__ b2,
    const float* __restrict__ Wih3, const float* __restrict__ b3,
    float* __restrict__ ws)
{
  int qk  = blockIdx.x;              // chunk id 0..511
  int dir = blockIdx.y;              // 0..3
  const float* Whh = dir==0?Whh0 : dir==1?Whh1 : dir==2?Whh2 : Whh3;
  const float* Wih = dir==0?Wih0 : dir==1?Wih1 : dir==2?Wih2 : Wih3;
  const float* bb  = dir==0?b0  : dir==1?b1  : dir==2?b2  : b3;
  int side = dir >> 1, bwd = dir & 1;
  const float* wh = ws + WH_OFF + side * 131072;
  float* enc = ws + ENC_OFF + side * 262144 + (bwd ? 32 : 0);
  int lane = threadIdx.x;

  __shared__ __align__(16) float hl[32];
  __shared__ __align__(16) float whs[kBURN + kCL][32];

  int tauOut = qk * kCL;
  int tau0   = tauOut - kBURN; if (tau0 < 0) tau0 = 0;
  int tauEnd = tauOut + kCL;
  int n = tauEnd - tau0;

  auto POS = [&](int tau){ return bwd ? (kNW - 1 - tau) : tau; };

  for (int i = lane; i < n * 32; i += 64){
    int j = i >> 5, k = i & 31;
    whs[j][k] = wh[(size_t)POS(tau0 + j) * 32 + k];
  }

  v2f wA[16], wB[16], pA[16], pB[16];
  #pragma unroll
  for (int q = 0; q < 8; ++q){
    float4 a  = *(const float4*)(Whh + lane * 32 + q * 4);
    float4 b4 = *(const float4*)(Whh + (lane + 64) * 32 + q * 4);
    wA[q*2+0] = (v2f){a.x, a.y};   wA[q*2+1] = (v2f){a.z, a.w};
    wB[q*2+0] = (v2f){b4.x, b4.y}; wB[q*2+1] = (v2f){b4.z, b4.w};
    float4 c4 = *(const float4*)(Wih + lane * 32 + q * 4);
    float4 d4 = *(const float4*)(Wih + (lane + 64) * 32 + q * 4);
    pA[q*2+0] = (v2f){c4.x, c4.y}; pA[q*2+1] = (v2f){c4.z, c4.w};
    pB[q*2+0] = (v2f){d4.x, d4.y}; pB[q*2+1] = (v2f){d4.z, d4.w};
  }
  float bA = bb[lane], bB = bb[lane + 64];
  if (lane < 32) hl[lane] = 0.f;
  float cst = 0.f;
  float kB = (lane < 32) ? -2.88539008f : -1.44269504f;
  float cB = (lane < 32) ? 2.f : 1.f;
  float dB = (lane < 32) ? -1.f : 0.f;

  for (int j = 0; j < n; ++j){
    int tau = tau0 + j;
    v2f w2[16];
    #pragma unroll
    for (int q = 0; q < 8; ++q){
      float4 wv = *(const float4*)(&whs[j][q*4]);
      w2[q*2+0] = (v2f){wv.x, wv.y}; w2[q*2+1] = (v2f){wv.z, wv.w};
    }
    v2f sa0 = {0.f,0.f}, sa1 = {0.f,0.f}, sb0 = {0.f,0.f}, sb1 = {0.f,0.f};
    #pragma unroll
    for (int k = 0; k < 8; ++k){
      sa0 = __builtin_elementwise_fma(pA[k],   w2[k],   sa0);
      sa1 = __builtin_elementwise_fma(pA[k+8], w2[k+8], sa1);
      sb0 = __builtin_elementwise_fma(pB[k],   w2[k],   sb0);
      sb1 = __builtin_elementwise_fma(pB[k+8], w2[k+8], sb1);
    }
    v2f hb[16];
    #pragma unroll
    for (int q = 0; q < 8; ++q){
      float4 hv = *(const float4*)(&hl[q*4]);
      hb[q*2+0] = (v2f){hv.x, hv.y}; hb[q*2+1] = (v2f){hv.z, hv.w};
    }
    v2f qa0 = {0.f,0.f}, qa1 = {0.f,0.f}, qb0 = {0.f,0.f}, qb1 = {0.f,0.f};
    #pragma unroll
    for (int k = 0; k < 8; ++k){
      qa0 = __builtin_elementwise_fma(wA[k],   hb[k],   qa0);
      qa1 = __builtin_elementwise_fma(wA[k+8], hb[k+8], qa1);
      qb0 = __builtin_elementwise_fma(wB[k],   hb[k],   qb0);
      qb1 = __builtin_elementwise_fma(wB[k+8], hb[k+8], qb1);
    }
    v2f va = (qa0 + qa1) + (sa0 + sa1);
    v2f vb = (qb0 + qb1) + (sb0 + sb1);
    float accA = bA + va.x + va.y;
    float accB = bB + vb.x + vb.y;
    float sA = fsig(accA);   // lo: sig(i), hi: sig(f)
    float sB = fmaf(cB, __builtin_amdgcn_rcpf(1.f + __builtin_amdgcn_exp2f(kB * accB)), dB);
                             // lo: tanh(g), hi: sig(o)
    float m   = sA * sB;
    float mex = __shfl(m, lane & 31, 64);
    cst = fmaf(sA, cst, mex);
    float h2 = sB * ftanh_(cst);
    if (lane >= 32){
      hl[lane - 32] = h2;
      if (tau >= tauOut) enc[(size_t)POS(tau) * 64 + (lane - 32)] = fsig(h2);
    }
  }
}

// ---------------- K3: out = f_enc @ e_enc.T  (K=64), 128x128 tiles, pk-f32 ----------------
__global__ __launch_bounds__(256) __attribute__((amdgpu_waves_per_eu(2, 4)))
void k_mm(const float* __restrict__ ws, float* __restrict__ out)
{
  const float* e_enc = ws + ENC_OFF;
  const float* f_enc = ws + ENC_OFF + 262144;
  __shared__ __align__(16) float fS[64][128];
  __shared__ __align__(16) float eS[64][128];
  int t = threadIdx.x;
  int row0 = blockIdx.y * 128;
  int col0 = blockIdx.x * 128;
  {
    int r = t & 127, kh = t >> 7;
    const float* fsrc = f_enc + (size_t)(row0 + r) * 64 + kh * 32;
    const float* esrc = e_enc + (size_t)(col0 + r) * 64 + kh * 32;
    #pragma unroll
    for (int q = 0; q < 8; ++q){
      float4 v = *(const float4*)(fsrc + q * 4);
      int k = kh * 32 + q * 4;
      fS[k+0][r] = v.x; fS[k+1][r] = v.y; fS[k+2][r] = v.z; fS[k+3][r] = v.w;
      float4 u = *(const float4*)(esrc + q * 4);
      eS[k+0][r] = u.x; eS[k+1][r] = u.y; eS[k+2][r] = u.z; eS[k+3][r] = u.w;
    }
  }
  __syncthreads();
  int tx = t & 15, ty = t >> 4;
  int r0 = ty * 8, c0 = tx * 8;
  v2f acc2[8][4];
  #pragma unroll
  for (int i = 0; i < 8; ++i)
    #pragma unroll
    for (int j = 0; j < 4; ++j) acc2[i][j] = (v2f){0.f, 0.f};

  #pragma unroll 4
  for (int k = 0; k < 64; ++k){
    float4 fa = *(const float4*)(&fS[k][r0]);
    float4 fb = *(const float4*)(&fS[k][r0 + 4]);
    float4 ea = *(const float4*)(&eS[k][c0]);
    float4 eb = *(const float4*)(&eS[k][c0 + 4]);
    float fr[8] = {fa.x, fa.y, fa.z, fa.w, fb.x, fb.y, fb.z, fb.w};
    v2f e2[4] = {(v2f){ea.x, ea.y}, (v2f){ea.z, ea.w},
                 (v2f){eb.x, eb.y}, (v2f){eb.z, eb.w}};
    #pragma unroll
    for (int i = 0; i < 8; ++i){
      v2f f2 = (v2f){fr[i], fr[i]};
      #pragma unroll
      for (int j = 0; j < 4; ++j)
        acc2[i][j] = __builtin_elementwise_fma(f2, e2[j], acc2[i][j]);
    }
  }
  #pragma unroll
  for (int i = 0; i < 8; ++i){
    float* dst = out + (size_t)(row0 + r0 + i) * 4096 + col0 + c0;
    *(float4*)(dst)     = make_float4(acc2[i][0].x, acc2[i][0].y, acc2[i][1].x, acc2[i][1].y);
    *(float4*)(dst + 4) = make_float4(acc2[i][2].x, acc2[i][2].y, acc2[i][3].x, acc2[i][3].y);
  }
}

extern "C" void kernel_launch(void* const* d_in, const int* in_sizes, int n_in,
                              void* d_out, int out_size, void* d_ws, size_t ws_size,
                              hipStream_t stream)
{
  const int* e_chars = (const int*)d_in[0];
  const int* e_lens  = (const int*)d_in[1];
  const int* f_chars = (const int*)d_in[2];
  const int* f_lens  = (const int*)d_in[3];
  // d_in[4] = diag (unused by reference)
  const float* embed_e = (const float*)d_in[5];
  const float* embed_f = (const float*)d_in[6];
  const float* eC_ih = (const float*)d_in[7];
  const float* eC_hh = (const float*)d_in[8];
  const float* eC_b  = (const float*)d_in[9];
  const float* fC_ih = (const float*)d_in[10];
  const float* fC_hh = (const float*)d_in[11];
  const float* fC_b  = (const float*)d_in[12];
  const float* efw_ih = (const float*)d_in[13];
  const float* efw_hh = (const float*)d_in[14];
  const float* efw_b  = (const float*)d_in[15];
  const float* ebw_ih = (const float*)d_in[16];
  const float* ebw_hh = (const float*)d_in[17];
  const float* ebw_b  = (const float*)d_in[18];
  const float* ffw_ih = (const float*)d_in[19];
  const float* ffw_hh = (const float*)d_in[20];
  const float* ffw_b  = (const float*)d_in[21];
  const float* fbw_ih = (const float*)d_in[22];
  const float* fbw_hh = (const float*)d_in[23];
  const float* fbw_b  = (const float*)d_in[24];
  float* ws  = (float*)d_ws;
  float* out = (float*)d_out;

  hipLaunchKernelGGL(k_tables, dim3(1024), dim3(256), 0, stream,
                     embed_e, embed_f, eC_ih, eC_b, fC_ih, fC_b, ws);
  hipLaunchKernelGGL(k_char, dim3(4096, 2), dim3(64), 0, stream,
                     e_chars, e_lens, f_chars, f_lens, eC_hh, fC_hh, ws);
  hipLaunchKernelGGL(k_word_par, dim3(kNW / kCL, 4), dim3(64), 0, stream,
                     efw_hh, ebw_hh, ffw_hh, fbw_hh,
                     efw_ih, efw_b, ebw_ih, ebw_b, ffw_ih, ffw_b, fbw_ih, fbw_b, ws);
  hipLaunchKernelGGL(k_mm, dim3(32, 32), dim3(256), 0, stream, ws, out);
}